// Round 1
// baseline (1275.091 us; speedup 1.0000x reference)
//
#include <hip/hip_runtime.h>
#include <hip/hip_bf16.h>
#include <math.h>

#define B_ 2
#define S_ 1000
#define D_ 1000

constexpr int CH = 50;   // scan chunk length
constexpr int NC = 20;   // number of chunks (CH*NC == S_)

__device__ __forceinline__ float silu_f(float v) { return v / (1.f + __expf(-v)); }

// ---------------- GEMM NT: C[m][n] = sum_k A[m][k]*Bw[n][k] (+bias[n]) -------
__global__ __launch_bounds__(256) void gemm_nt(const float* __restrict__ A,
                                               const float* __restrict__ Bw,
                                               const float* __restrict__ bias,
                                               float* __restrict__ C,
                                               int M, int N, int K) {
  constexpr int TM = 64, TN = 64, TK = 16;
  __shared__ float As[TK][TM + 1];
  __shared__ float Bs[TK][TN + 1];
  const int m0 = blockIdx.x * TM, n0 = blockIdx.y * TN;
  const int tid = threadIdx.x;
  const int tr = tid >> 4, tc = tid & 15;
  const int lrow = tid >> 2;        // 0..63
  const int kc = (tid & 3) * 4;     // 0,4,8,12
  float acc[4][4] = {};
  for (int k0 = 0; k0 < K; k0 += TK) {
#pragma unroll
    for (int j = 0; j < 4; ++j) {
      int k = k0 + kc + j;
      float av = 0.f, bv = 0.f;
      if (k < K) {
        if (m0 + lrow < M) av = A[(size_t)(m0 + lrow) * K + k];
        if (n0 + lrow < N) bv = Bw[(size_t)(n0 + lrow) * K + k];
      }
      As[kc + j][lrow] = av;
      Bs[kc + j][lrow] = bv;
    }
    __syncthreads();
#pragma unroll
    for (int kk = 0; kk < TK; ++kk) {
      float a[4], bv[4];
#pragma unroll
      for (int i = 0; i < 4; ++i) a[i] = As[kk][tr + 16 * i];
#pragma unroll
      for (int j = 0; j < 4; ++j) bv[j] = Bs[kk][tc + 16 * j];
#pragma unroll
      for (int i = 0; i < 4; ++i)
#pragma unroll
        for (int j = 0; j < 4; ++j)
          acc[i][j] = fmaf(a[i], bv[j], acc[i][j]);
    }
    __syncthreads();
  }
#pragma unroll
  for (int i = 0; i < 4; ++i) {
    int m = m0 + tr + 16 * i;
    if (m >= M) continue;
#pragma unroll
    for (int j = 0; j < 4; ++j) {
      int n = n0 + tc + 16 * j;
      if (n >= N) continue;
      C[(size_t)m * N + n] = acc[i][j] + (bias ? bias[n] : 0.f);
    }
  }
}

// ------------- conv (dense, K=3 taps over feature axis) + silu ---------------
// out[b][o][h] = silu( sum_{i<1000,k<3} p1[b][i][h+k-1] * cw[o][i][k] )
// stored as x2[b][s=o][d=h]
__global__ __launch_bounds__(256) void conv_silu(const float* __restrict__ p1,
                                                 const float* __restrict__ cw,
                                                 float* __restrict__ x2) {
  constexpr int TO = 64, TH = 64, TI = 16;
  __shared__ float Ws[TI][3][TO];
  __shared__ float Ps[TI][TH + 2];
  const int b = blockIdx.z;
  const int o0 = blockIdx.x * TO, h0 = blockIdx.y * TH;
  const int tid = threadIdx.x;
  const int tr = tid >> 4, tc = tid & 15;
  float acc[4][4] = {};
  for (int ic = 0; ic < S_; ic += TI) {
    {
      int o = o0 + (tid >> 2);
      int base = (tid & 3) * 12;
#pragma unroll
      for (int j = 0; j < 12; ++j) {
        int idx = base + j;
        int il = idx / 3, k = idx - il * 3;
        float v = 0.f;
        if (o < D_ && ic + il < S_) v = cw[(size_t)(o * S_ + ic + il) * 3 + k];
        Ws[il][k][o - o0] = v;
      }
    }
    for (int idx = tid; idx < TI * (TH + 2); idx += 256) {
      int r = idx / (TH + 2), c2 = idx - r * (TH + 2);
      int hh = h0 - 1 + c2;
      float v = 0.f;
      if (ic + r < S_ && hh >= 0 && hh < D_) v = p1[((size_t)(b * S_) + ic + r) * D_ + hh];
      Ps[r][c2] = v;
    }
    __syncthreads();
#pragma unroll
    for (int kk = 0; kk < TI; ++kk) {
      float w0[4], w1[4], w2[4], pv[4][3];
#pragma unroll
      for (int i = 0; i < 4; ++i) {
        w0[i] = Ws[kk][0][tr + 16 * i];
        w1[i] = Ws[kk][1][tr + 16 * i];
        w2[i] = Ws[kk][2][tr + 16 * i];
      }
#pragma unroll
      for (int j = 0; j < 4; ++j) {
        pv[j][0] = Ps[kk][tc + 16 * j];
        pv[j][1] = Ps[kk][tc + 16 * j + 1];
        pv[j][2] = Ps[kk][tc + 16 * j + 2];
      }
#pragma unroll
      for (int i = 0; i < 4; ++i)
#pragma unroll
        for (int j = 0; j < 4; ++j)
          acc[i][j] += w0[i] * pv[j][0] + w1[i] * pv[j][1] + w2[i] * pv[j][2];
    }
    __syncthreads();
  }
#pragma unroll
  for (int i = 0; i < 4; ++i) {
    int o = o0 + tr + 16 * i;
    if (o >= D_) continue;
#pragma unroll
    for (int j = 0; j < 4; ++j) {
      int h = h0 + tc + 16 * j;
      if (h >= D_) continue;
      x2[((size_t)(b * S_) + o) * D_ + h] = silu_f(acc[i][j]);
    }
  }
}

// -------- delta[m][d] = softplus( sum_{j<32} dBC[m][j]*W[d][j] + bias[d] ) ---
__global__ __launch_bounds__(256) void delta_kernel(const float* __restrict__ dBC,
                                                    const float* __restrict__ W,
                                                    const float* __restrict__ bias,
                                                    float* __restrict__ delta) {
  const int d = blockIdx.x * 256 + threadIdx.x;
  const int mBase = blockIdx.y * 16;
  __shared__ float rs[16][32];
  for (int idx = threadIdx.x; idx < 16 * 32; idx += 256) {
    int r = idx >> 5, c = idx & 31;
    rs[r][c] = dBC[(size_t)(mBase + r) * 64 + c];
  }
  __syncthreads();
  if (d >= D_) return;
  float w[32];
#pragma unroll
  for (int j = 0; j < 32; ++j) w[j] = W[d * 32 + j];
  const float bb = bias[d];
  for (int r = 0; r < 16; ++r) {
    float acc = bb;
#pragma unroll
    for (int j = 0; j < 32; ++j) acc = fmaf(rs[r][j], w[j], acc);
    float sp = (acc > 20.f) ? acc : log1pf(__expf(acc));
    delta[(size_t)(mBase + r) * D_ + d] = sp;
  }
}

// ------------------- selective scan, 3-pass chunked --------------------------
__global__ __launch_bounds__(256) void scan1(const float* __restrict__ delta,
                                             const float* __restrict__ x2,
                                             const float* __restrict__ dBC,
                                             const float* __restrict__ A_log,
                                             float* __restrict__ hfin,
                                             float* __restrict__ psum) {
  const int d = blockIdx.x * 256 + threadIdx.x;
  const int c = blockIdx.y, b = blockIdx.z;
  __shared__ float Bs[CH][16];
  for (int idx = threadIdx.x; idx < CH * 16; idx += 256) {
    int r = idx >> 4, n = idx & 15;
    Bs[r][n] = dBC[(size_t)(b * S_ + c * CH + r) * 64 + 32 + n];
  }
  __syncthreads();
  if (d >= D_) return;
  float a[16];
#pragma unroll
  for (int n = 0; n < 16; ++n) a[n] = -__expf(A_log[d * 16 + n]);
  float h[16] = {};
  float dsum = 0.f;
  const float* dp = delta + ((size_t)(b * S_ + c * CH)) * D_ + d;
  const float* xp = x2 + ((size_t)(b * S_ + c * CH)) * D_ + d;
  for (int l = 0; l < CH; ++l) {
    float dlt = dp[(size_t)l * D_];
    float xv = xp[(size_t)l * D_];
    dsum += dlt;
    float dx = dlt * xv;
#pragma unroll
    for (int n = 0; n < 16; ++n) {
      float da = __expf(dlt * a[n]);
      h[n] = fmaf(da, h[n], dx * Bs[l][n]);
    }
  }
  float* hb = hfin + (((size_t)b * NC + c) * D_ + d) * 16;
#pragma unroll
  for (int n = 0; n < 16; ++n) hb[n] = h[n];
  psum[((size_t)b * NC + c) * D_ + d] = dsum;
}

__global__ __launch_bounds__(256) void scan2(const float* __restrict__ hfin,
                                             const float* __restrict__ psum,
                                             const float* __restrict__ A_log,
                                             float* __restrict__ hin) {
  const int t = blockIdx.x * 256 + threadIdx.x;
  if (t >= B_ * D_) return;
  const int b = t / D_, d = t - b * D_;
  float a[16];
#pragma unroll
  for (int n = 0; n < 16; ++n) a[n] = -__expf(A_log[d * 16 + n]);
  float h[16] = {};
  for (int c = 0; c < NC; ++c) {
    float* hp = hin + (((size_t)b * NC + c) * D_ + d) * 16;
#pragma unroll
    for (int n = 0; n < 16; ++n) hp[n] = h[n];
    float ps = psum[((size_t)b * NC + c) * D_ + d];
    const float* hf = hfin + (((size_t)b * NC + c) * D_ + d) * 16;
#pragma unroll
    for (int n = 0; n < 16; ++n) {
      float P = __expf(a[n] * ps);
      h[n] = fmaf(P, h[n], hf[n]);
    }
  }
}

__global__ __launch_bounds__(256) void scan3(const float* __restrict__ delta,
                                             const float* __restrict__ x2,
                                             const float* __restrict__ dBC,
                                             const float* __restrict__ A_log,
                                             const float* __restrict__ Dp,
                                             const float* __restrict__ hin,
                                             float* __restrict__ y) {
  const int d = blockIdx.x * 256 + threadIdx.x;
  const int c = blockIdx.y, b = blockIdx.z;
  __shared__ float Bs[CH][16];
  __shared__ float Cs[CH][16];
  for (int idx = threadIdx.x; idx < CH * 32; idx += 256) {
    int r = idx >> 5, col = idx & 31;
    float v = dBC[(size_t)(b * S_ + c * CH + r) * 64 + 32 + col];
    if (col < 16) Bs[r][col] = v;
    else Cs[r][col - 16] = v;
  }
  __syncthreads();
  if (d >= D_) return;
  float a[16];
#pragma unroll
  for (int n = 0; n < 16; ++n) a[n] = -__expf(A_log[d * 16 + n]);
  float h[16];
  const float* hp = hin + (((size_t)b * NC + c) * D_ + d) * 16;
#pragma unroll
  for (int n = 0; n < 16; ++n) h[n] = hp[n];
  const float dpv = Dp[d];
  const float* dp = delta + ((size_t)(b * S_ + c * CH)) * D_ + d;
  const float* xp = x2 + ((size_t)(b * S_ + c * CH)) * D_ + d;
  float* yp = y + ((size_t)(b * S_ + c * CH)) * D_ + d;
  for (int l = 0; l < CH; ++l) {
    float dlt = dp[(size_t)l * D_];
    float xv = xp[(size_t)l * D_];
    float dx = dlt * xv;
    float yv = 0.f;
#pragma unroll
    for (int n = 0; n < 16; ++n) {
      float da = __expf(dlt * a[n]);
      h[n] = fmaf(da, h[n], dx * Bs[l][n]);
      yv = fmaf(h[n], Cs[l][n], yv);
    }
    yp[(size_t)l * D_] = fmaf(dpv, xv, yv);
  }
}

// ------------------------- mult = silu(path1) * y ----------------------------
__global__ __launch_bounds__(256) void mult_kernel(const float* __restrict__ p1,
                                                   float* __restrict__ y, int n) {
  int i = blockIdx.x * 256 + threadIdx.x;
  if (i < n) {
    float v = p1[i];
    y[i] = silu_f(v) * y[i];
  }
}

extern "C" void kernel_launch(void* const* d_in, const int* in_sizes, int n_in,
                              void* d_out, int out_size, void* d_ws, size_t ws_size,
                              hipStream_t stream) {
  const float* x        = (const float*)d_in[0];
  const float* proj_w   = (const float*)d_in[1];
  const float* proj_b   = (const float*)d_in[2];
  const float* conv_w   = (const float*)d_in[3];
  const float* deltaBC_w= (const float*)d_in[4];
  const float* dt_proj_w= (const float*)d_in[5];
  const float* dt_proj_b= (const float*)d_in[6];
  const float* A_log    = (const float*)d_in[7];
  const float* Dp       = (const float*)d_in[8];
  float* out = (float*)d_out;

  // workspace layout (floats): total ~9.45M floats = 37.8 MB
  float* ws    = (float*)d_ws;
  float* P1    = ws;                 // 2,000,000
  float* X2    = P1 + 2000000;       // 2,000,000
  float* DBC   = X2 + 2000000;       //   128,000
  float* DELTA = DBC + 128000;       // 2,000,000
  float* Y     = DELTA + 2000000;    // 2,000,000
  float* HFIN  = Y + 2000000;        //   640,000
  float* PSUM  = HFIN + 640000;      //    40,000
  float* HIN   = PSUM + 40000;       //   640,000

  dim3 blk(256);
  // 1. path1 = x @ proj_w.T + proj_b   (M=2000, N=1000, K=1000)
  gemm_nt<<<dim3(32, 16), blk, 0, stream>>>(x, proj_w, proj_b, P1, B_ * S_, D_, D_);
  // 2. x2 = silu(conv(path1))
  conv_silu<<<dim3(16, 16, B_), blk, 0, stream>>>(P1, conv_w, X2);
  // 3. dBC = x2 @ deltaBC_w.T          (M=2000, N=64, K=1000)
  gemm_nt<<<dim3(32, 1), blk, 0, stream>>>(X2, deltaBC_w, nullptr, DBC, B_ * S_, 64, D_);
  // 4. delta = softplus(dBC[:, :32] @ dt_proj_w.T + dt_proj_b)
  delta_kernel<<<dim3(4, 125), blk, 0, stream>>>(DBC, dt_proj_w, dt_proj_b, DELTA);
  // 5-7. chunked selective scan -> Y
  scan1<<<dim3(4, NC, B_), blk, 0, stream>>>(DELTA, X2, DBC, A_log, HFIN, PSUM);
  scan2<<<dim3(8), blk, 0, stream>>>(HFIN, PSUM, A_log, HIN);
  scan3<<<dim3(4, NC, B_), blk, 0, stream>>>(DELTA, X2, DBC, A_log, Dp, HIN, Y);
  // 8. mult = silu(path1) * Y  (in place in Y)
  mult_kernel<<<dim3((B_ * S_ * D_ + 255) / 256), blk, 0, stream>>>(P1, Y, B_ * S_ * D_);
  // 9. out = mult @ proj_w.T + proj_b
  gemm_nt<<<dim3(32, 16), blk, 0, stream>>>(Y, proj_w, proj_b, out, B_ * S_, D_, D_);
}

// Round 2
// 292.484 us; speedup vs baseline: 4.3595x; 4.3595x over previous
//
#include <hip/hip_runtime.h>
#include <hip/hip_bf16.h>
#include <math.h>

#define B_ 2
#define S_ 1000
#define D_ 1000

constexpr int CH = 50;   // scan chunk length
constexpr int NC = 20;   // number of chunks (CH*NC == S_)

typedef __attribute__((ext_vector_type(8))) short bf16x8;   // 8 bf16 (4 VGPRs)
typedef __attribute__((ext_vector_type(4))) float f32x4;    // MFMA accumulator

__device__ __forceinline__ float silu_f(float v) { return v / (1.f + __expf(-v)); }

// async global->LDS, 16B per lane, wave-uniform LDS base + lane*16
__device__ __forceinline__ void gld16(const void* g, void* l) {
  __builtin_amdgcn_global_load_lds(
      (const __attribute__((address_space(1))) unsigned int*)g,
      (__attribute__((address_space(3))) unsigned int*)l, 16, 0, 0);
}

// ----------------- conversion / repack kernels (bf16, zero-padded) ----------
// src [R][C] f32 -> dst [Rp][1024] bf16, zero pad
__global__ __launch_bounds__(256) void cvt_pad(const float* __restrict__ src,
                                               __hip_bfloat16* __restrict__ dst,
                                               int R, int C) {
  int idx = blockIdx.x * 256 + threadIdx.x;
  int r = idx >> 10, c = idx & 1023;
  float v = 0.f;
  if (r < R && c < C) v = src[(size_t)r * C + c];
  dst[idx] = __float2bfloat16(v);
}

// conv_w[(o*1000+i)*3+k] f32 -> cwb[k][1024 o][1024 i] bf16, zero pad
__global__ __launch_bounds__(256) void cvt_conv(const float* __restrict__ cw,
                                                __hip_bfloat16* __restrict__ cwb) {
  int idx = blockIdx.x * 256 + threadIdx.x;   // over 1024*1024
  int o = idx >> 10, i = idx & 1023;
  float v0 = 0.f, v1 = 0.f, v2 = 0.f;
  if (o < D_ && i < S_) {
    const float* p = cw + ((size_t)o * S_ + i) * 3;
    v0 = p[0]; v1 = p[1]; v2 = p[2];
  }
  cwb[idx]             = __float2bfloat16(v0);
  cwb[idx + 1048576]   = __float2bfloat16(v1);
  cwb[idx + 2097152]   = __float2bfloat16(v2);
}

// P1 f32 [2][1000 s][1000 d] -> P1T bf16 [2][1056 rows][1024 s], row r = d+1
// (row 0 = d=-1 halo = 0, rows >=1001 = 0, s-pad = 0)
__global__ __launch_bounds__(256) void transpose_p1(const float* __restrict__ p1,
                                                    __hip_bfloat16* __restrict__ p1t) {
  __shared__ float t[32][33];
  const int b = blockIdx.z;
  const int s0 = blockIdx.x * 32;
  const int R0 = blockIdx.y * 32;
  const int tx = threadIdx.x & 31, ty = threadIdx.x >> 5;
#pragma unroll
  for (int q = 0; q < 4; ++q) {
    int sl = ty + 8 * q;
    int s = s0 + sl;
    int dd = R0 - 1 + tx;
    float v = 0.f;
    if (s < S_ && dd >= 0 && dd < D_) v = p1[((size_t)b * S_ + s) * D_ + dd];
    t[sl][tx] = v;
  }
  __syncthreads();
#pragma unroll
  for (int q = 0; q < 4; ++q) {
    int rl = ty + 8 * q;
    p1t[((size_t)b * 1056 + R0 + rl) * 1024 + s0 + tx] = __float2bfloat16(t[tx][rl]);
  }
}

// --------------- MFMA GEMM NT: C[m][n] = sum_k A[m][k]*Bt[n][k] + bias[n] ----
// A [Mp][1024] bf16, Bt [1024][1024] bf16, BM=BN=64, BK=32, 4 waves (2x2)
__global__ __launch_bounds__(256) void gemm_mfma(const __hip_bfloat16* __restrict__ A,
                                                 const __hip_bfloat16* __restrict__ Bt,
                                                 const float* __restrict__ bias,
                                                 float* __restrict__ C,
                                                 int M, int N, int ldc) {
  __shared__ __hip_bfloat16 Al[64 * 32];
  __shared__ __hip_bfloat16 Bl[64 * 32];
  const int tid = threadIdx.x, lane = tid & 63, w = tid >> 6;
  const int wr = (w >> 1) & 1, wc = w & 1;
  const int m0 = blockIdx.x * 64, n0 = blockIdx.y * 64;
  const int srow = 16 * w + (lane >> 2);
  const int scol = (lane & 3) * 8;
  const __hip_bfloat16* gA = A + (size_t)(m0 + srow) * 1024 + scol;
  const __hip_bfloat16* gB = Bt + (size_t)(n0 + srow) * 1024 + scol;
  __hip_bfloat16* lA = &Al[w * 512];
  __hip_bfloat16* lB = &Bl[w * 512];
  f32x4 acc[2][2] = {};
  const int fr = lane & 15, fq = lane >> 4;
  for (int k0 = 0; k0 < 1024; k0 += 32) {
    __syncthreads();
    gld16(gA + k0, lA);
    gld16(gB + k0, lB);
    asm volatile("s_waitcnt vmcnt(0)" ::: "memory");
    __syncthreads();
    bf16x8 af[2], bfv[2];
#pragma unroll
    for (int i = 0; i < 2; ++i)
      af[i] = *(const bf16x8*)&Al[(wr * 32 + i * 16 + fr) * 32 + fq * 8];
#pragma unroll
    for (int j = 0; j < 2; ++j)
      bfv[j] = *(const bf16x8*)&Bl[(wc * 32 + j * 16 + fr) * 32 + fq * 8];
#pragma unroll
    for (int i = 0; i < 2; ++i)
#pragma unroll
      for (int j = 0; j < 2; ++j)
        acc[i][j] = __builtin_amdgcn_mfma_f32_16x16x32_bf16(af[i], bfv[j], acc[i][j], 0, 0, 0);
  }
#pragma unroll
  for (int i = 0; i < 2; ++i) {
#pragma unroll
    for (int j = 0; j < 2; ++j) {
      const int mb = m0 + wr * 32 + i * 16 + fq * 4;
      const int n = n0 + wc * 32 + j * 16 + fr;
      if (n < N) {
        float bv = bias ? bias[n] : 0.f;
#pragma unroll
        for (int r = 0; r < 4; ++r)
          if (mb + r < M) C[(size_t)(mb + r) * ldc + n] = acc[i][j][r] + bv;
      }
    }
  }
}

// -------- conv as implicit MFMA GEMM: X2[b][o][h] = silu(sum_{i,t} W_t[o][i]*P1T[b][h+t-1][i])
__global__ __launch_bounds__(256) void conv_mfma(const __hip_bfloat16* __restrict__ Wt,   // [3][1024][1024]
                                                 const __hip_bfloat16* __restrict__ P1T,  // [2][1056][1024]
                                                 float* __restrict__ X2) {
  __shared__ __hip_bfloat16 Al[3 * 64 * 32];
  __shared__ __hip_bfloat16 Bl[80 * 32];
  const int b = blockIdx.z;
  const int o0 = blockIdx.x * 64, h0 = blockIdx.y * 64;
  const int tid = threadIdx.x, lane = tid & 63, w = tid >> 6;
  const int wr = (w >> 1) & 1, wc = w & 1;
  const int srow = (lane >> 2);
  const int scol = (lane & 3) * 8;
  const int fr = lane & 15, fq = lane >> 4;
  f32x4 acc[2][2] = {};
  const __hip_bfloat16* gB0 = P1T + ((size_t)b * 1056 + h0 + w * 16 + srow) * 1024 + scol;
  const __hip_bfloat16* gB4 = P1T + ((size_t)b * 1056 + h0 + 64 + srow) * 1024 + scol;
  for (int k0 = 0; k0 < 1024; k0 += 32) {
    __syncthreads();
#pragma unroll
    for (int q = 0; q < 3; ++q)
      gld16(Wt + (((size_t)q * 1024) + o0 + w * 16 + srow) * 1024 + k0 + scol,
            &Al[q * 2048 + w * 512]);
    gld16(gB0 + k0, &Bl[w * 512]);
    if (w == 0) gld16(gB4 + k0, &Bl[4 * 512]);
    asm volatile("s_waitcnt vmcnt(0)" ::: "memory");
    __syncthreads();
    bf16x8 af[3][2], bfv[3][2];
#pragma unroll
    for (int t = 0; t < 3; ++t)
#pragma unroll
      for (int i = 0; i < 2; ++i)
        af[t][i] = *(const bf16x8*)&Al[t * 2048 + (wr * 32 + i * 16 + fr) * 32 + fq * 8];
#pragma unroll
    for (int t = 0; t < 3; ++t)
#pragma unroll
      for (int j = 0; j < 2; ++j)
        bfv[t][j] = *(const bf16x8*)&Bl[(wc * 32 + j * 16 + fr + t) * 32 + fq * 8];
#pragma unroll
    for (int t = 0; t < 3; ++t)
#pragma unroll
      for (int i = 0; i < 2; ++i)
#pragma unroll
        for (int j = 0; j < 2; ++j)
          acc[i][j] = __builtin_amdgcn_mfma_f32_16x16x32_bf16(af[t][i], bfv[t][j], acc[i][j], 0, 0, 0);
  }
#pragma unroll
  for (int i = 0; i < 2; ++i) {
#pragma unroll
    for (int j = 0; j < 2; ++j) {
      const int ob = o0 + wr * 32 + i * 16 + fq * 4;
      const int h = h0 + wc * 32 + j * 16 + fr;
      if (h < D_) {
#pragma unroll
        for (int r = 0; r < 4; ++r)
          if (ob + r < D_)
            X2[((size_t)b * S_ + ob + r) * D_ + h] = silu_f(acc[i][j][r]);
      }
    }
  }
}

// ---------------- f32 GEMM NT (small: dBC) ----------------------------------
__global__ __launch_bounds__(256) void gemm_nt(const float* __restrict__ A,
                                               const float* __restrict__ Bw,
                                               const float* __restrict__ bias,
                                               float* __restrict__ C,
                                               int M, int N, int K) {
  constexpr int TM = 64, TN = 64, TK = 16;
  __shared__ float As[TK][TM + 1];
  __shared__ float Bs[TK][TN + 1];
  const int m0 = blockIdx.x * TM, n0 = blockIdx.y * TN;
  const int tid = threadIdx.x;
  const int tr = tid >> 4, tc = tid & 15;
  const int lrow = tid >> 2;
  const int kc = (tid & 3) * 4;
  float acc[4][4] = {};
  for (int k0 = 0; k0 < K; k0 += TK) {
#pragma unroll
    for (int j = 0; j < 4; ++j) {
      int k = k0 + kc + j;
      float av = 0.f, bv = 0.f;
      if (k < K) {
        if (m0 + lrow < M) av = A[(size_t)(m0 + lrow) * K + k];
        if (n0 + lrow < N) bv = Bw[(size_t)(n0 + lrow) * K + k];
      }
      As[kc + j][lrow] = av;
      Bs[kc + j][lrow] = bv;
    }
    __syncthreads();
#pragma unroll
    for (int kk = 0; kk < TK; ++kk) {
      float a[4], bv[4];
#pragma unroll
      for (int i = 0; i < 4; ++i) a[i] = As[kk][tr + 16 * i];
#pragma unroll
      for (int j = 0; j < 4; ++j) bv[j] = Bs[kk][tc + 16 * j];
#pragma unroll
      for (int i = 0; i < 4; ++i)
#pragma unroll
        for (int j = 0; j < 4; ++j)
          acc[i][j] = fmaf(a[i], bv[j], acc[i][j]);
    }
    __syncthreads();
  }
#pragma unroll
  for (int i = 0; i < 4; ++i) {
    int m = m0 + tr + 16 * i;
    if (m >= M) continue;
#pragma unroll
    for (int j = 0; j < 4; ++j) {
      int n = n0 + tc + 16 * j;
      if (n >= N) continue;
      C[(size_t)m * N + n] = acc[i][j] + (bias ? bias[n] : 0.f);
    }
  }
}

// -------- delta[m][d] = softplus( sum_{j<32} dBC[m][j]*W[d][j] + bias[d] ) ---
__global__ __launch_bounds__(256) void delta_kernel(const float* __restrict__ dBC,
                                                    const float* __restrict__ W,
                                                    const float* __restrict__ bias,
                                                    float* __restrict__ delta) {
  const int d = blockIdx.x * 256 + threadIdx.x;
  const int mBase = blockIdx.y * 16;
  __shared__ float rs[16][32];
  for (int idx = threadIdx.x; idx < 16 * 32; idx += 256) {
    int r = idx >> 5, c = idx & 31;
    rs[r][c] = dBC[(size_t)(mBase + r) * 64 + c];
  }
  __syncthreads();
  if (d >= D_) return;
  float w[32];
#pragma unroll
  for (int j = 0; j < 32; ++j) w[j] = W[d * 32 + j];
  const float bb = bias[d];
  for (int r = 0; r < 16; ++r) {
    float acc = bb;
#pragma unroll
    for (int j = 0; j < 32; ++j) acc = fmaf(rs[r][j], w[j], acc);
    float sp = (acc > 20.f) ? acc : log1pf(__expf(acc));
    delta[(size_t)(mBase + r) * D_ + d] = sp;
  }
}

// ------------------- selective scan, 3-pass chunked --------------------------
__global__ __launch_bounds__(256) void scan1(const float* __restrict__ delta,
                                             const float* __restrict__ x2,
                                             const float* __restrict__ dBC,
                                             const float* __restrict__ A_log,
                                             float* __restrict__ hfin,
                                             float* __restrict__ psum) {
  const int d = blockIdx.x * 256 + threadIdx.x;
  const int c = blockIdx.y, b = blockIdx.z;
  __shared__ float Bs[CH][16];
  for (int idx = threadIdx.x; idx < CH * 16; idx += 256) {
    int r = idx >> 4, n = idx & 15;
    Bs[r][n] = dBC[(size_t)(b * S_ + c * CH + r) * 64 + 32 + n];
  }
  __syncthreads();
  if (d >= D_) return;
  float a[16];
#pragma unroll
  for (int n = 0; n < 16; ++n) a[n] = -__expf(A_log[d * 16 + n]);
  float h[16] = {};
  float dsum = 0.f;
  const float* dp = delta + ((size_t)(b * S_ + c * CH)) * D_ + d;
  const float* xp = x2 + ((size_t)(b * S_ + c * CH)) * D_ + d;
  for (int l = 0; l < CH; ++l) {
    float dlt = dp[(size_t)l * D_];
    float xv = xp[(size_t)l * D_];
    dsum += dlt;
    float dx = dlt * xv;
#pragma unroll
    for (int n = 0; n < 16; ++n) {
      float da = __expf(dlt * a[n]);
      h[n] = fmaf(da, h[n], dx * Bs[l][n]);
    }
  }
  float* hb = hfin + (((size_t)b * NC + c) * D_ + d) * 16;
#pragma unroll
  for (int n = 0; n < 16; ++n) hb[n] = h[n];
  psum[((size_t)b * NC + c) * D_ + d] = dsum;
}

__global__ __launch_bounds__(256) void scan2(const float* __restrict__ hfin,
                                             const float* __restrict__ psum,
                                             const float* __restrict__ A_log,
                                             float* __restrict__ hin) {
  const int t = blockIdx.x * 256 + threadIdx.x;
  if (t >= B_ * D_) return;
  const int b = t / D_, d = t - b * D_;
  float a[16];
#pragma unroll
  for (int n = 0; n < 16; ++n) a[n] = -__expf(A_log[d * 16 + n]);
  float h[16] = {};
  for (int c = 0; c < NC; ++c) {
    float* hp = hin + (((size_t)b * NC + c) * D_ + d) * 16;
#pragma unroll
    for (int n = 0; n < 16; ++n) hp[n] = h[n];
    float ps = psum[((size_t)b * NC + c) * D_ + d];
    const float* hf = hfin + (((size_t)b * NC + c) * D_ + d) * 16;
#pragma unroll
    for (int n = 0; n < 16; ++n) {
      float P = __expf(a[n] * ps);
      h[n] = fmaf(P, h[n], hf[n]);
    }
  }
}

__global__ __launch_bounds__(256) void scan3(const float* __restrict__ delta,
                                             const float* __restrict__ x2,
                                             const float* __restrict__ dBC,
                                             const float* __restrict__ A_log,
                                             const float* __restrict__ Dp,
                                             const float* __restrict__ hin,
                                             float* __restrict__ y) {
  const int d = blockIdx.x * 256 + threadIdx.x;
  const int c = blockIdx.y, b = blockIdx.z;
  __shared__ float Bs[CH][16];
  __shared__ float Cs[CH][16];
  for (int idx = threadIdx.x; idx < CH * 32; idx += 256) {
    int r = idx >> 5, col = idx & 31;
    float v = dBC[(size_t)(b * S_ + c * CH + r) * 64 + 32 + col];
    if (col < 16) Bs[r][col] = v;
    else Cs[r][col - 16] = v;
  }
  __syncthreads();
  if (d >= D_) return;
  float a[16];
#pragma unroll
  for (int n = 0; n < 16; ++n) a[n] = -__expf(A_log[d * 16 + n]);
  float h[16];
  const float* hp = hin + (((size_t)b * NC + c) * D_ + d) * 16;
#pragma unroll
  for (int n = 0; n < 16; ++n) h[n] = hp[n];
  const float dpv = Dp[d];
  const float* dp = delta + ((size_t)(b * S_ + c * CH)) * D_ + d;
  const float* xp = x2 + ((size_t)(b * S_ + c * CH)) * D_ + d;
  float* yp = y + ((size_t)(b * S_ + c * CH)) * D_ + d;
  for (int l = 0; l < CH; ++l) {
    float dlt = dp[(size_t)l * D_];
    float xv = xp[(size_t)l * D_];
    float dx = dlt * xv;
    float yv = 0.f;
#pragma unroll
    for (int n = 0; n < 16; ++n) {
      float da = __expf(dlt * a[n]);
      h[n] = fmaf(da, h[n], dx * Bs[l][n]);
      yv = fmaf(h[n], Cs[l][n], yv);
    }
    yp[(size_t)l * D_] = fmaf(dpv, xv, yv);
  }
}

// ---------- mult_bf: MBF[m][k] = bf16( silu(P1[m][k]) * Y[m][k] ), padded ----
__global__ __launch_bounds__(256) void mult_bf(const float* __restrict__ p1,
                                               const float* __restrict__ y,
                                               __hip_bfloat16* __restrict__ mbf) {
  int idx = blockIdx.x * 256 + threadIdx.x;  // over 2048*1024
  int m = idx >> 10, k = idx & 1023;
  float v = 0.f;
  if (m < B_ * S_ && k < D_) {
    float a = p1[(size_t)m * D_ + k];
    v = silu_f(a) * y[(size_t)m * D_ + k];
  }
  mbf[idx] = __float2bfloat16(v);
}

extern "C" void kernel_launch(void* const* d_in, const int* in_sizes, int n_in,
                              void* d_out, int out_size, void* d_ws, size_t ws_size,
                              hipStream_t stream) {
  const float* x        = (const float*)d_in[0];
  const float* proj_w   = (const float*)d_in[1];
  const float* proj_b   = (const float*)d_in[2];
  const float* conv_w   = (const float*)d_in[3];
  const float* deltaBC_w= (const float*)d_in[4];
  const float* dt_proj_w= (const float*)d_in[5];
  const float* dt_proj_b= (const float*)d_in[6];
  const float* A_log    = (const float*)d_in[7];
  const float* Dp       = (const float*)d_in[8];
  float* out = (float*)d_out;

  char* w8 = (char*)d_ws;
  float* P1    = (float*)(w8 + 0);          //  8,000,000 B
  float* X2    = (float*)(w8 + 8000000);    //  8,000,000
  float* DBC   = (float*)(w8 + 16000000);   //    512,000
  float* DELTA = (float*)(w8 + 16512000);   //  8,000,000
  float* Y     = (float*)(w8 + 24512000);   //  8,000,000
  float* HFIN  = (float*)(w8 + 32512000);   //  2,560,000
  float* PSUM  = (float*)(w8 + 35072000);   //    160,000
  float* HIN   = (float*)(w8 + 35232000);   //  2,560,000
  __hip_bfloat16* XBF = (__hip_bfloat16*)(w8 + 37792000);  // [2048][1024] 4,194,304
  __hip_bfloat16* WBF = (__hip_bfloat16*)(w8 + 41986304);  // [1024][1024] 2,097,152
  __hip_bfloat16* CWB = (__hip_bfloat16*)(w8 + 44083456);  // [3][1024][1024] 6,291,456
  __hip_bfloat16* P1T = (__hip_bfloat16*)(w8 + 50374912);  // [2][1056][1024] 4,325,376
  __hip_bfloat16* MBF = (__hip_bfloat16*)(w8 + 54700288);  // [2048][1024] 4,194,304
  // total 58,894,592 B

  dim3 blk(256);
  // bf16 conversions
  cvt_pad<<<dim3(8192), blk, 0, stream>>>(x, XBF, B_ * S_, D_);
  cvt_pad<<<dim3(4096), blk, 0, stream>>>(proj_w, WBF, D_, D_);
  cvt_conv<<<dim3(4096), blk, 0, stream>>>(conv_w, CWB);
  // 1. path1 = x @ proj_w.T + proj_b  (MFMA)
  gemm_mfma<<<dim3(32, 16), blk, 0, stream>>>(XBF, WBF, proj_b, P1, B_ * S_, D_, D_);
  // 1b. transpose path1 -> P1T (bf16, halo-padded)
  transpose_p1<<<dim3(32, 33, B_), blk, 0, stream>>>(P1, P1T);
  // 2. x2 = silu(conv(path1))  (implicit MFMA GEMM)
  conv_mfma<<<dim3(16, 16, B_), blk, 0, stream>>>(CWB, P1T, X2);
  // 3. dBC = x2 @ deltaBC_w.T  (small f32 GEMM)
  gemm_nt<<<dim3(32, 1), blk, 0, stream>>>(X2, deltaBC_w, nullptr, DBC, B_ * S_, 64, D_);
  // 4. delta = softplus(dBC[:, :32] @ dt_proj_w.T + dt_proj_b)
  delta_kernel<<<dim3(4, 125), blk, 0, stream>>>(DBC, dt_proj_w, dt_proj_b, DELTA);
  // 5-7. chunked selective scan -> Y
  scan1<<<dim3(4, NC, B_), blk, 0, stream>>>(DELTA, X2, DBC, A_log, HFIN, PSUM);
  scan2<<<dim3(8), blk, 0, stream>>>(HFIN, PSUM, A_log, HIN);
  scan3<<<dim3(4, NC, B_), blk, 0, stream>>>(DELTA, X2, DBC, A_log, Dp, HIN, Y);
  // 8. mult = silu(path1) * Y -> bf16 padded
  mult_bf<<<dim3(8192), blk, 0, stream>>>(P1, Y, MBF);
  // 9. out = mult @ proj_w.T + proj_b  (MFMA)
  gemm_mfma<<<dim3(32, 16), blk, 0, stream>>>(MBF, WBF, proj_b, out, B_ * S_, D_, D_);
}

// Round 3
// 194.321 us; speedup vs baseline: 6.5618x; 1.5052x over previous
//
#include <hip/hip_runtime.h>
#include <hip/hip_bf16.h>
#include <math.h>

#define B_ 2
#define S_ 1000
#define D_ 1000

constexpr int CH = 25;   // scan chunk length
constexpr int NC = 40;   // number of chunks (CH*NC == S_)

typedef __attribute__((ext_vector_type(8))) short bf16x8;   // 8 bf16 (4 VGPRs)
typedef __attribute__((ext_vector_type(4))) float f32x4;    // MFMA accumulator

__device__ __forceinline__ float silu_f(float v) { return v / (1.f + __expf(-v)); }

// async global->LDS, 16B per lane, wave-uniform LDS base + lane*16
__device__ __forceinline__ void gld16(const void* g, void* l) {
  __builtin_amdgcn_global_load_lds(
      (const __attribute__((address_space(1))) unsigned int*)g,
      (__attribute__((address_space(3))) unsigned int*)l, 16, 0, 0);
}

// ----------------- conversion / repack kernels (bf16, zero-padded) ----------
__global__ __launch_bounds__(256) void cvt_pad(const float* __restrict__ src,
                                               __hip_bfloat16* __restrict__ dst,
                                               int R, int C) {
  int idx = blockIdx.x * 256 + threadIdx.x;
  int r = idx >> 10, c = idx & 1023;
  float v = 0.f;
  if (r < R && c < C) v = src[(size_t)r * C + c];
  dst[idx] = __float2bfloat16(v);
}

// conv_w[(o*1000+i)*3+k] f32 -> cwb[k][1024 o][1024 i] bf16, zero pad
__global__ __launch_bounds__(256) void cvt_conv(const float* __restrict__ cw,
                                                __hip_bfloat16* __restrict__ cwb) {
  int idx = blockIdx.x * 256 + threadIdx.x;   // over 1024*1024
  int o = idx >> 10, i = idx & 1023;
  float v0 = 0.f, v1 = 0.f, v2 = 0.f;
  if (o < D_ && i < S_) {
    const float* p = cw + ((size_t)o * S_ + i) * 3;
    v0 = p[0]; v1 = p[1]; v2 = p[2];
  }
  cwb[idx]             = __float2bfloat16(v0);
  cwb[idx + 1048576]   = __float2bfloat16(v1);
  cwb[idx + 2097152]   = __float2bfloat16(v2);
}

// P1 f32 [2][1000 s][1000 d] -> P1T bf16 [2][1056 rows][1024 s], row r = d+1
__global__ __launch_bounds__(256) void transpose_p1(const float* __restrict__ p1,
                                                    __hip_bfloat16* __restrict__ p1t) {
  __shared__ float t[32][33];
  const int b = blockIdx.z;
  const int s0 = blockIdx.x * 32;
  const int R0 = blockIdx.y * 32;
  const int tx = threadIdx.x & 31, ty = threadIdx.x >> 5;
#pragma unroll
  for (int q = 0; q < 4; ++q) {
    int sl = ty + 8 * q;
    int s = s0 + sl;
    int dd = R0 - 1 + tx;
    float v = 0.f;
    if (s < S_ && dd >= 0 && dd < D_) v = p1[((size_t)b * S_ + s) * D_ + dd];
    t[sl][tx] = v;
  }
  __syncthreads();
#pragma unroll
  for (int q = 0; q < 4; ++q) {
    int rl = ty + 8 * q;
    p1t[((size_t)b * 1056 + R0 + rl) * 1024 + s0 + tx] = __float2bfloat16(t[tx][rl]);
  }
}

// --------------- MFMA GEMM NT: C[m][n] = sum_k A[m][k]*Bt[n][k] + bias[n] ----
__global__ __launch_bounds__(256) void gemm_mfma(const __hip_bfloat16* __restrict__ A,
                                                 const __hip_bfloat16* __restrict__ Bt,
                                                 const float* __restrict__ bias,
                                                 float* __restrict__ C,
                                                 int M, int N, int ldc) {
  __shared__ __hip_bfloat16 Al[64 * 32];
  __shared__ __hip_bfloat16 Bl[64 * 32];
  const int tid = threadIdx.x, lane = tid & 63, w = tid >> 6;
  const int wr = (w >> 1) & 1, wc = w & 1;
  const int m0 = blockIdx.x * 64, n0 = blockIdx.y * 64;
  const int srow = 16 * w + (lane >> 2);
  const int scol = (lane & 3) * 8;
  const __hip_bfloat16* gA = A + (size_t)(m0 + srow) * 1024 + scol;
  const __hip_bfloat16* gB = Bt + (size_t)(n0 + srow) * 1024 + scol;
  __hip_bfloat16* lA = &Al[w * 512];
  __hip_bfloat16* lB = &Bl[w * 512];
  f32x4 acc[2][2] = {};
  const int fr = lane & 15, fq = lane >> 4;
  for (int k0 = 0; k0 < 1024; k0 += 32) {
    __syncthreads();
    gld16(gA + k0, lA);
    gld16(gB + k0, lB);
    asm volatile("s_waitcnt vmcnt(0)" ::: "memory");
    __syncthreads();
    bf16x8 af[2], bfv[2];
#pragma unroll
    for (int i = 0; i < 2; ++i)
      af[i] = *(const bf16x8*)&Al[(wr * 32 + i * 16 + fr) * 32 + fq * 8];
#pragma unroll
    for (int j = 0; j < 2; ++j)
      bfv[j] = *(const bf16x8*)&Bl[(wc * 32 + j * 16 + fr) * 32 + fq * 8];
#pragma unroll
    for (int i = 0; i < 2; ++i)
#pragma unroll
      for (int j = 0; j < 2; ++j)
        acc[i][j] = __builtin_amdgcn_mfma_f32_16x16x32_bf16(af[i], bfv[j], acc[i][j], 0, 0, 0);
  }
#pragma unroll
  for (int i = 0; i < 2; ++i) {
#pragma unroll
    for (int j = 0; j < 2; ++j) {
      const int mb = m0 + wr * 32 + i * 16 + fq * 4;
      const int n = n0 + wc * 32 + j * 16 + fr;
      if (n < N) {
        float bv = bias ? bias[n] : 0.f;
#pragma unroll
        for (int r = 0; r < 4; ++r)
          if (mb + r < M) C[(size_t)(mb + r) * ldc + n] = acc[i][j][r] + bv;
      }
    }
  }
}

// -------- conv as implicit MFMA GEMM -----------------------------------------
__global__ __launch_bounds__(256) void conv_mfma(const __hip_bfloat16* __restrict__ Wt,   // [3][1024][1024]
                                                 const __hip_bfloat16* __restrict__ P1T,  // [2][1056][1024]
                                                 float* __restrict__ X2) {
  __shared__ __hip_bfloat16 Al[3 * 64 * 32];
  __shared__ __hip_bfloat16 Bl[80 * 32];
  const int b = blockIdx.z;
  const int o0 = blockIdx.x * 64, h0 = blockIdx.y * 64;
  const int tid = threadIdx.x, lane = tid & 63, w = tid >> 6;
  const int wr = (w >> 1) & 1, wc = w & 1;
  const int srow = (lane >> 2);
  const int scol = (lane & 3) * 8;
  const int fr = lane & 15, fq = lane >> 4;
  f32x4 acc[2][2] = {};
  const __hip_bfloat16* gB0 = P1T + ((size_t)b * 1056 + h0 + w * 16 + srow) * 1024 + scol;
  const __hip_bfloat16* gB4 = P1T + ((size_t)b * 1056 + h0 + 64 + srow) * 1024 + scol;
  for (int k0 = 0; k0 < 1024; k0 += 32) {
    __syncthreads();
#pragma unroll
    for (int q = 0; q < 3; ++q)
      gld16(Wt + (((size_t)q * 1024) + o0 + w * 16 + srow) * 1024 + k0 + scol,
            &Al[q * 2048 + w * 512]);
    gld16(gB0 + k0, &Bl[w * 512]);
    if (w == 0) gld16(gB4 + k0, &Bl[4 * 512]);
    asm volatile("s_waitcnt vmcnt(0)" ::: "memory");
    __syncthreads();
    bf16x8 af[3][2], bfv[3][2];
#pragma unroll
    for (int t = 0; t < 3; ++t)
#pragma unroll
      for (int i = 0; i < 2; ++i)
        af[t][i] = *(const bf16x8*)&Al[t * 2048 + (wr * 32 + i * 16 + fr) * 32 + fq * 8];
#pragma unroll
    for (int t = 0; t < 3; ++t)
#pragma unroll
      for (int j = 0; j < 2; ++j)
        bfv[t][j] = *(const bf16x8*)&Bl[(wc * 32 + j * 16 + fr + t) * 32 + fq * 8];
#pragma unroll
    for (int t = 0; t < 3; ++t)
#pragma unroll
      for (int i = 0; i < 2; ++i)
#pragma unroll
        for (int j = 0; j < 2; ++j)
          acc[i][j] = __builtin_amdgcn_mfma_f32_16x16x32_bf16(af[t][i], bfv[t][j], acc[i][j], 0, 0, 0);
  }
#pragma unroll
  for (int i = 0; i < 2; ++i) {
#pragma unroll
    for (int j = 0; j < 2; ++j) {
      const int ob = o0 + wr * 32 + i * 16 + fq * 4;
      const int h = h0 + wc * 32 + j * 16 + fr;
      if (h < D_) {
#pragma unroll
        for (int r = 0; r < 4; ++r)
          if (ob + r < D_)
            X2[((size_t)b * S_ + ob + r) * D_ + h] = silu_f(acc[i][j][r]);
      }
    }
  }
}

// ---------------- f32 split-K GEMM NT for dBC (N=64) -------------------------
// part[kc][m][64] += sum over K-chunk kc
__global__ __launch_bounds__(256) void gemm_nt_splitk(const float* __restrict__ A,
                                                      const float* __restrict__ Bw,
                                                      float* __restrict__ part,
                                                      int M, int N, int K) {
  constexpr int TM = 64, TN = 64, TK = 16;
  __shared__ float As[TK][TM + 1];
  __shared__ float Bs[TK][TN + 1];
  const int m0 = blockIdx.x * TM, n0 = 0;
  const int kc = blockIdx.y;
  const int kbeg = kc * 128;
  const int kend = min(K, kbeg + 128);
  const int tid = threadIdx.x;
  const int tr = tid >> 4, tc = tid & 15;
  const int lrow = tid >> 2;
  const int kcc = (tid & 3) * 4;
  float acc[4][4] = {};
  for (int k0 = kbeg; k0 < kend; k0 += TK) {
#pragma unroll
    for (int j = 0; j < 4; ++j) {
      int k = k0 + kcc + j;
      float av = 0.f, bv = 0.f;
      if (k < K) {
        if (m0 + lrow < M) av = A[(size_t)(m0 + lrow) * K + k];
        if (n0 + lrow < N) bv = Bw[(size_t)(n0 + lrow) * K + k];
      }
      As[kcc + j][lrow] = av;
      Bs[kcc + j][lrow] = bv;
    }
    __syncthreads();
#pragma unroll
    for (int kk = 0; kk < TK; ++kk) {
      float a[4], bv[4];
#pragma unroll
      for (int i = 0; i < 4; ++i) a[i] = As[kk][tr + 16 * i];
#pragma unroll
      for (int j = 0; j < 4; ++j) bv[j] = Bs[kk][tc + 16 * j];
#pragma unroll
      for (int i = 0; i < 4; ++i)
#pragma unroll
        for (int j = 0; j < 4; ++j)
          acc[i][j] = fmaf(a[i], bv[j], acc[i][j]);
    }
    __syncthreads();
  }
  float* pb = part + (size_t)kc * 2048 * 64;
#pragma unroll
  for (int i = 0; i < 4; ++i) {
    int m = m0 + tr + 16 * i;
    if (m >= M) continue;
#pragma unroll
    for (int j = 0; j < 4; ++j) {
      int n = tc + 16 * j;
      pb[(size_t)m * 64 + n] = acc[i][j];
    }
  }
}

// DBC[m][n] = sum_{kc<8} part[kc][m][n]
__global__ __launch_bounds__(256) void reduce_dbc(const float* __restrict__ part,
                                                  float* __restrict__ dbc, int M) {
  int idx = blockIdx.x * 256 + threadIdx.x;   // over M*64
  if (idx >= M * 64) return;
  float s = 0.f;
#pragma unroll
  for (int kc = 0; kc < 8; ++kc) s += part[(size_t)kc * 2048 * 64 + idx];
  dbc[idx] = s;
}

// -------- delta[m][d] = softplus( sum_{j<32} dBC[m][j]*W[d][j] + bias[d] ) ---
__global__ __launch_bounds__(256) void delta_kernel(const float* __restrict__ dBC,
                                                    const float* __restrict__ W,
                                                    const float* __restrict__ bias,
                                                    float* __restrict__ delta) {
  const int d = blockIdx.x * 256 + threadIdx.x;
  const int mBase = blockIdx.y * 16;
  __shared__ float rs[16][32];
  for (int idx = threadIdx.x; idx < 16 * 32; idx += 256) {
    int r = idx >> 5, c = idx & 31;
    rs[r][c] = dBC[(size_t)(mBase + r) * 64 + c];
  }
  __syncthreads();
  if (d >= D_) return;
  float w[32];
#pragma unroll
  for (int j = 0; j < 32; ++j) w[j] = W[d * 32 + j];
  const float bb = bias[d];
  for (int r = 0; r < 16; ++r) {
    float acc = bb;
#pragma unroll
    for (int j = 0; j < 32; ++j) acc = fmaf(rs[r][j], w[j], acc);
    float sp = (acc > 20.f) ? acc : log1pf(__expf(acc));
    delta[(size_t)(mBase + r) * D_ + d] = sp;
  }
}

// ------------------- selective scan, 3-pass chunked --------------------------
__global__ __launch_bounds__(256) void scan1(const float* __restrict__ delta,
                                             const float* __restrict__ x2,
                                             const float* __restrict__ dBC,
                                             const float* __restrict__ A_log,
                                             float* __restrict__ hfin,
                                             float* __restrict__ psum) {
  const int d = blockIdx.x * 256 + threadIdx.x;
  const int c = blockIdx.y, b = blockIdx.z;
  __shared__ float Bs[CH][16];
  for (int idx = threadIdx.x; idx < CH * 16; idx += 256) {
    int r = idx >> 4, n = idx & 15;
    Bs[r][n] = dBC[(size_t)(b * S_ + c * CH + r) * 64 + 32 + n];
  }
  __syncthreads();
  if (d >= D_) return;
  float a[16];
#pragma unroll
  for (int n = 0; n < 16; ++n) a[n] = -__expf(A_log[d * 16 + n]);
  float h[16] = {};
  float dsum = 0.f;
  const float* dp = delta + ((size_t)(b * S_ + c * CH)) * D_ + d;
  const float* xp = x2 + ((size_t)(b * S_ + c * CH)) * D_ + d;
  for (int l = 0; l < CH; ++l) {
    float dlt = dp[(size_t)l * D_];
    float xv = xp[(size_t)l * D_];
    dsum += dlt;
    float dx = dlt * xv;
#pragma unroll
    for (int n = 0; n < 16; ++n) {
      float da = __expf(dlt * a[n]);
      h[n] = fmaf(da, h[n], dx * Bs[l][n]);
    }
  }
  float* hb = hfin + (((size_t)b * NC + c) * D_ + d) * 16;
#pragma unroll
  for (int n = 0; n < 16; ++n) hb[n] = h[n];
  psum[((size_t)b * NC + c) * D_ + d] = dsum;
}

__global__ __launch_bounds__(256) void scan2(const float* __restrict__ hfin,
                                             const float* __restrict__ psum,
                                             const float* __restrict__ A_log,
                                             float* __restrict__ hin) {
  const int t = blockIdx.x * 256 + threadIdx.x;
  if (t >= B_ * D_) return;
  const int b = t / D_, d = t - b * D_;
  float a[16];
#pragma unroll
  for (int n = 0; n < 16; ++n) a[n] = -__expf(A_log[d * 16 + n]);
  float h[16] = {};
  for (int c = 0; c < NC; ++c) {
    float* hp = hin + (((size_t)b * NC + c) * D_ + d) * 16;
#pragma unroll
    for (int n = 0; n < 16; ++n) hp[n] = h[n];
    float ps = psum[((size_t)b * NC + c) * D_ + d];
    const float* hf = hfin + (((size_t)b * NC + c) * D_ + d) * 16;
#pragma unroll
    for (int n = 0; n < 16; ++n) {
      float P = __expf(a[n] * ps);
      h[n] = fmaf(P, h[n], hf[n]);
    }
  }
}

__global__ __launch_bounds__(256) void scan3(const float* __restrict__ delta,
                                             const float* __restrict__ x2,
                                             const float* __restrict__ dBC,
                                             const float* __restrict__ A_log,
                                             const float* __restrict__ Dp,
                                             const float* __restrict__ hin,
                                             float* __restrict__ y) {
  const int d = blockIdx.x * 256 + threadIdx.x;
  const int c = blockIdx.y, b = blockIdx.z;
  __shared__ float Bs[CH][16];
  __shared__ float Cs[CH][16];
  for (int idx = threadIdx.x; idx < CH * 32; idx += 256) {
    int r = idx >> 5, col = idx & 31;
    float v = dBC[(size_t)(b * S_ + c * CH + r) * 64 + 32 + col];
    if (col < 16) Bs[r][col] = v;
    else Cs[r][col - 16] = v;
  }
  __syncthreads();
  if (d >= D_) return;
  float a[16];
#pragma unroll
  for (int n = 0; n < 16; ++n) a[n] = -__expf(A_log[d * 16 + n]);
  float h[16];
  const float* hp = hin + (((size_t)b * NC + c) * D_ + d) * 16;
#pragma unroll
  for (int n = 0; n < 16; ++n) h[n] = hp[n];
  const float dpv = Dp[d];
  const float* dp = delta + ((size_t)(b * S_ + c * CH)) * D_ + d;
  const float* xp = x2 + ((size_t)(b * S_ + c * CH)) * D_ + d;
  float* yp = y + ((size_t)(b * S_ + c * CH)) * D_ + d;
  for (int l = 0; l < CH; ++l) {
    float dlt = dp[(size_t)l * D_];
    float xv = xp[(size_t)l * D_];
    float dx = dlt * xv;
    float yv = 0.f;
#pragma unroll
    for (int n = 0; n < 16; ++n) {
      float da = __expf(dlt * a[n]);
      h[n] = fmaf(da, h[n], dx * Bs[l][n]);
      yv = fmaf(h[n], Cs[l][n], yv);
    }
    yp[(size_t)l * D_] = fmaf(dpv, xv, yv);
  }
}

// ---------- mult_bf: MBF[m][k] = bf16( silu(P1[m][k]) * Y[m][k] ), padded ----
__global__ __launch_bounds__(256) void mult_bf(const float* __restrict__ p1,
                                               const float* __restrict__ y,
                                               __hip_bfloat16* __restrict__ mbf) {
  int idx = blockIdx.x * 256 + threadIdx.x;  // over 2048*1024
  int m = idx >> 10, k = idx & 1023;
  float v = 0.f;
  if (m < B_ * S_ && k < D_) {
    float a = p1[(size_t)m * D_ + k];
    v = silu_f(a) * y[(size_t)m * D_ + k];
  }
  mbf[idx] = __float2bfloat16(v);
}

extern "C" void kernel_launch(void* const* d_in, const int* in_sizes, int n_in,
                              void* d_out, int out_size, void* d_ws, size_t ws_size,
                              hipStream_t stream) {
  const float* x        = (const float*)d_in[0];
  const float* proj_w   = (const float*)d_in[1];
  const float* proj_b   = (const float*)d_in[2];
  const float* conv_w   = (const float*)d_in[3];
  const float* deltaBC_w= (const float*)d_in[4];
  const float* dt_proj_w= (const float*)d_in[5];
  const float* dt_proj_b= (const float*)d_in[6];
  const float* A_log    = (const float*)d_in[7];
  const float* Dp       = (const float*)d_in[8];
  float* out = (float*)d_out;

  char* w8 = (char*)d_ws;
  float* P1    = (float*)(w8 + 0);          //  8,000,000 B
  float* X2    = (float*)(w8 + 8000000);    //  8,000,000
  float* DBC   = (float*)(w8 + 16000000);   //    512,000
  float* DELTA = (float*)(w8 + 16512000);   //  8,000,000
  float* Y     = (float*)(w8 + 24512000);   //  8,000,000
  __hip_bfloat16* XBF = (__hip_bfloat16*)(w8 + 32512000);  // [2048][1024]      4,194,304
  __hip_bfloat16* WBF = (__hip_bfloat16*)(w8 + 36706304);  // [1024][1024]      2,097,152
  __hip_bfloat16* CWB = (__hip_bfloat16*)(w8 + 38803456);  // [3][1024][1024]   6,291,456
  __hip_bfloat16* P1T = (__hip_bfloat16*)(w8 + 45094912);  // [2][1056][1024]   4,325,376
  __hip_bfloat16* MBF = (__hip_bfloat16*)(w8 + 49420288);  // [2048][1024]      4,194,304
  // scan scratch aliased over CWB+P1T (dead after conv_mfma):
  float* HFIN  = (float*)(w8 + 38803456);   // 5,120,000  (B*NC*D*16)
  float* PSUM  = (float*)(w8 + 43923456);   //   320,000
  float* HIN   = (float*)(w8 + 44243456);   // 5,120,000  -> ends 49,363,456
  // split-K partials aliased over MBF (dead until mult_bf):
  float* PART  = (float*)(w8 + 49420288);   // 4,194,304  [8][2048][64]
  // total ws use: 53,614,592 B

  dim3 blk(256);
  // bf16 conversions
  cvt_pad<<<dim3(8192), blk, 0, stream>>>(x, XBF, B_ * S_, D_);
  cvt_pad<<<dim3(4096), blk, 0, stream>>>(proj_w, WBF, D_, D_);
  cvt_conv<<<dim3(4096), blk, 0, stream>>>(conv_w, CWB);
  // 1. path1 = x @ proj_w.T + proj_b  (MFMA)
  gemm_mfma<<<dim3(32, 16), blk, 0, stream>>>(XBF, WBF, proj_b, P1, B_ * S_, D_, D_);
  // 1b. transpose path1 -> P1T (bf16, halo-padded)
  transpose_p1<<<dim3(32, 33, B_), blk, 0, stream>>>(P1, P1T);
  // 2. x2 = silu(conv(path1))  (implicit MFMA GEMM)
  conv_mfma<<<dim3(16, 16, B_), blk, 0, stream>>>(CWB, P1T, X2);
  // 3. dBC = x2 @ deltaBC_w.T  (f32 split-K + reduce)
  gemm_nt_splitk<<<dim3(32, 8), blk, 0, stream>>>(X2, deltaBC_w, PART, B_ * S_, 64, D_);
  reduce_dbc<<<dim3(500), blk, 0, stream>>>(PART, DBC, B_ * S_);
  // 4. delta = softplus(dBC[:, :32] @ dt_proj_w.T + dt_proj_b)
  delta_kernel<<<dim3(4, 125), blk, 0, stream>>>(DBC, dt_proj_w, dt_proj_b, DELTA);
  // 5-7. chunked selective scan -> Y
  scan1<<<dim3(4, NC, B_), blk, 0, stream>>>(DELTA, X2, DBC, A_log, HFIN, PSUM);
  scan2<<<dim3(8), blk, 0, stream>>>(HFIN, PSUM, A_log, HIN);
  scan3<<<dim3(4, NC, B_), blk, 0, stream>>>(DELTA, X2, DBC, A_log, Dp, HIN, Y);
  // 8. mult = silu(path1) * Y -> bf16 padded
  mult_bf<<<dim3(8192), blk, 0, stream>>>(P1, Y, MBF);
  // 9. out = mult @ proj_w.T + proj_b  (MFMA)
  gemm_mfma<<<dim3(32, 16), blk, 0, stream>>>(MBF, WBF, proj_b, out, B_ * S_, D_, D_);
}

// Round 4
// 160.655 us; speedup vs baseline: 7.9368x; 1.2096x over previous
//
#include <hip/hip_runtime.h>
#include <hip/hip_bf16.h>
#include <math.h>

#define B_ 2
#define S_ 1000
#define D_ 1000

constexpr int CH = 25;   // scan chunk length
constexpr int NC = 40;   // number of chunks (CH*NC == S_)

typedef __attribute__((ext_vector_type(8))) short bf16x8;   // 8 bf16 (4 VGPRs)
typedef __attribute__((ext_vector_type(4))) float f32x4;    // MFMA accumulator

__device__ __forceinline__ float silu_f(float v) { return v / (1.f + __expf(-v)); }

// async global->LDS, 16B per lane, wave-uniform LDS base + lane*16
__device__ __forceinline__ void gld16(const void* g, void* l) {
  __builtin_amdgcn_global_load_lds(
      (const __attribute__((address_space(1))) unsigned int*)g,
      (__attribute__((address_space(3))) unsigned int*)l, 16, 0, 0);
}

// ----------------- conversion / repack kernels (bf16, zero-padded) ----------
__global__ __launch_bounds__(256) void cvt_pad(const float* __restrict__ src,
                                               __hip_bfloat16* __restrict__ dst,
                                               int R, int C) {
  int idx = blockIdx.x * 256 + threadIdx.x;
  int r = idx >> 10, c = idx & 1023;
  float v = 0.f;
  if (r < R && c < C) v = src[(size_t)r * C + c];
  dst[idx] = __float2bfloat16(v);
}

// conv_w[(o*1000+i)*3+k] f32 -> cwb[k][1024 o][1024 i] bf16, zero pad
__global__ __launch_bounds__(256) void cvt_conv(const float* __restrict__ cw,
                                                __hip_bfloat16* __restrict__ cwb) {
  int idx = blockIdx.x * 256 + threadIdx.x;   // over 1024*1024
  int o = idx >> 10, i = idx & 1023;
  float v0 = 0.f, v1 = 0.f, v2 = 0.f;
  if (o < D_ && i < S_) {
    const float* p = cw + ((size_t)o * S_ + i) * 3;
    v0 = p[0]; v1 = p[1]; v2 = p[2];
  }
  cwb[idx]             = __float2bfloat16(v0);
  cwb[idx + 1048576]   = __float2bfloat16(v1);
  cwb[idx + 2097152]   = __float2bfloat16(v2);
}

// P1 f32 [2][1000 s][1000 d] -> P1T bf16 [2][1056 rows][1024 s], row r = d+1
__global__ __launch_bounds__(256) void transpose_p1(const float* __restrict__ p1,
                                                    __hip_bfloat16* __restrict__ p1t) {
  __shared__ float t[32][33];
  const int b = blockIdx.z;
  const int s0 = blockIdx.x * 32;
  const int R0 = blockIdx.y * 32;
  const int tx = threadIdx.x & 31, ty = threadIdx.x >> 5;
#pragma unroll
  for (int q = 0; q < 4; ++q) {
    int sl = ty + 8 * q;
    int s = s0 + sl;
    int dd = R0 - 1 + tx;
    float v = 0.f;
    if (s < S_ && dd >= 0 && dd < D_) v = p1[((size_t)b * S_ + s) * D_ + dd];
    t[sl][tx] = v;
  }
  __syncthreads();
#pragma unroll
  for (int q = 0; q < 4; ++q) {
    int rl = ty + 8 * q;
    p1t[((size_t)b * 1056 + R0 + rl) * 1024 + s0 + tx] = __float2bfloat16(t[tx][rl]);
  }
}

// --------------- MFMA GEMM NT: C[m][n] = sum_k A[m][k]*Bt[n][k] + bias[n] ----
__global__ __launch_bounds__(256) void gemm_mfma(const __hip_bfloat16* __restrict__ A,
                                                 const __hip_bfloat16* __restrict__ Bt,
                                                 const float* __restrict__ bias,
                                                 float* __restrict__ C,
                                                 int M, int N, int ldc) {
  __shared__ __hip_bfloat16 Al[64 * 32];
  __shared__ __hip_bfloat16 Bl[64 * 32];
  const int tid = threadIdx.x, lane = tid & 63, w = tid >> 6;
  const int wr = (w >> 1) & 1, wc = w & 1;
  const int m0 = blockIdx.x * 64, n0 = blockIdx.y * 64;
  const int srow = 16 * w + (lane >> 2);
  const int scol = (lane & 3) * 8;
  const __hip_bfloat16* gA = A + (size_t)(m0 + srow) * 1024 + scol;
  const __hip_bfloat16* gB = Bt + (size_t)(n0 + srow) * 1024 + scol;
  __hip_bfloat16* lA = &Al[w * 512];
  __hip_bfloat16* lB = &Bl[w * 512];
  f32x4 acc[2][2] = {};
  const int fr = lane & 15, fq = lane >> 4;
  for (int k0 = 0; k0 < 1024; k0 += 32) {
    __syncthreads();
    gld16(gA + k0, lA);
    gld16(gB + k0, lB);
    asm volatile("s_waitcnt vmcnt(0)" ::: "memory");
    __syncthreads();
    bf16x8 af[2], bfv[2];
#pragma unroll
    for (int i = 0; i < 2; ++i)
      af[i] = *(const bf16x8*)&Al[(wr * 32 + i * 16 + fr) * 32 + fq * 8];
#pragma unroll
    for (int j = 0; j < 2; ++j)
      bfv[j] = *(const bf16x8*)&Bl[(wc * 32 + j * 16 + fr) * 32 + fq * 8];
#pragma unroll
    for (int i = 0; i < 2; ++i)
#pragma unroll
      for (int j = 0; j < 2; ++j)
        acc[i][j] = __builtin_amdgcn_mfma_f32_16x16x32_bf16(af[i], bfv[j], acc[i][j], 0, 0, 0);
  }
#pragma unroll
  for (int i = 0; i < 2; ++i) {
#pragma unroll
    for (int j = 0; j < 2; ++j) {
      const int mb = m0 + wr * 32 + i * 16 + fq * 4;
      const int n = n0 + wc * 32 + j * 16 + fr;
      if (n < N) {
        float bv = bias ? bias[n] : 0.f;
#pragma unroll
        for (int r = 0; r < 4; ++r)
          if (mb + r < M) C[(size_t)(mb + r) * ldc + n] = acc[i][j][r] + bv;
      }
    }
  }
}

// -------- conv as implicit MFMA GEMM -----------------------------------------
__global__ __launch_bounds__(256) void conv_mfma(const __hip_bfloat16* __restrict__ Wt,   // [3][1024][1024]
                                                 const __hip_bfloat16* __restrict__ P1T,  // [2][1056][1024]
                                                 float* __restrict__ X2) {
  __shared__ __hip_bfloat16 Al[3 * 64 * 32];
  __shared__ __hip_bfloat16 Bl[80 * 32];
  const int b = blockIdx.z;
  const int o0 = blockIdx.x * 64, h0 = blockIdx.y * 64;
  const int tid = threadIdx.x, lane = tid & 63, w = tid >> 6;
  const int wr = (w >> 1) & 1, wc = w & 1;
  const int srow = (lane >> 2);
  const int scol = (lane & 3) * 8;
  const int fr = lane & 15, fq = lane >> 4;
  f32x4 acc[2][2] = {};
  const __hip_bfloat16* gB0 = P1T + ((size_t)b * 1056 + h0 + w * 16 + srow) * 1024 + scol;
  const __hip_bfloat16* gB4 = P1T + ((size_t)b * 1056 + h0 + 64 + srow) * 1024 + scol;
  for (int k0 = 0; k0 < 1024; k0 += 32) {
    __syncthreads();
#pragma unroll
    for (int q = 0; q < 3; ++q)
      gld16(Wt + (((size_t)q * 1024) + o0 + w * 16 + srow) * 1024 + k0 + scol,
            &Al[q * 2048 + w * 512]);
    gld16(gB0 + k0, &Bl[w * 512]);
    if (w == 0) gld16(gB4 + k0, &Bl[4 * 512]);
    asm volatile("s_waitcnt vmcnt(0)" ::: "memory");
    __syncthreads();
    bf16x8 af[3][2], bfv[3][2];
#pragma unroll
    for (int t = 0; t < 3; ++t)
#pragma unroll
      for (int i = 0; i < 2; ++i)
        af[t][i] = *(const bf16x8*)&Al[t * 2048 + (wr * 32 + i * 16 + fr) * 32 + fq * 8];
#pragma unroll
    for (int t = 0; t < 3; ++t)
#pragma unroll
      for (int j = 0; j < 2; ++j)
        bfv[t][j] = *(const bf16x8*)&Bl[(wc * 32 + j * 16 + fr + t) * 32 + fq * 8];
#pragma unroll
    for (int t = 0; t < 3; ++t)
#pragma unroll
      for (int i = 0; i < 2; ++i)
#pragma unroll
        for (int j = 0; j < 2; ++j)
          acc[i][j] = __builtin_amdgcn_mfma_f32_16x16x32_bf16(af[t][i], bfv[t][j], acc[i][j], 0, 0, 0);
  }
#pragma unroll
  for (int i = 0; i < 2; ++i) {
#pragma unroll
    for (int j = 0; j < 2; ++j) {
      const int ob = o0 + wr * 32 + i * 16 + fq * 4;
      const int h = h0 + wc * 32 + j * 16 + fr;
      if (h < D_) {
#pragma unroll
        for (int r = 0; r < 4; ++r)
          if (ob + r < D_)
            X2[((size_t)b * S_ + ob + r) * D_ + h] = silu_f(acc[i][j][r]);
      }
    }
  }
}

// ---------------- f32 split-K GEMM NT for dBC (N=64) -------------------------
__global__ __launch_bounds__(256) void gemm_nt_splitk(const float* __restrict__ A,
                                                      const float* __restrict__ Bw,
                                                      float* __restrict__ part,
                                                      int M, int N, int K) {
  constexpr int TM = 64, TN = 64, TK = 16;
  __shared__ float As[TK][TM + 1];
  __shared__ float Bs[TK][TN + 1];
  const int m0 = blockIdx.x * TM, n0 = 0;
  const int kc = blockIdx.y;
  const int kbeg = kc * 128;
  const int kend = min(K, kbeg + 128);
  const int tid = threadIdx.x;
  const int tr = tid >> 4, tc = tid & 15;
  const int lrow = tid >> 2;
  const int kcc = (tid & 3) * 4;
  float acc[4][4] = {};
  for (int k0 = kbeg; k0 < kend; k0 += TK) {
#pragma unroll
    for (int j = 0; j < 4; ++j) {
      int k = k0 + kcc + j;
      float av = 0.f, bv = 0.f;
      if (k < K) {
        if (m0 + lrow < M) av = A[(size_t)(m0 + lrow) * K + k];
        if (n0 + lrow < N) bv = Bw[(size_t)(n0 + lrow) * K + k];
      }
      As[kcc + j][lrow] = av;
      Bs[kcc + j][lrow] = bv;
    }
    __syncthreads();
#pragma unroll
    for (int kk = 0; kk < TK; ++kk) {
      float a[4], bv[4];
#pragma unroll
      for (int i = 0; i < 4; ++i) a[i] = As[kk][tr + 16 * i];
#pragma unroll
      for (int j = 0; j < 4; ++j) bv[j] = Bs[kk][tc + 16 * j];
#pragma unroll
      for (int i = 0; i < 4; ++i)
#pragma unroll
        for (int j = 0; j < 4; ++j)
          acc[i][j] = fmaf(a[i], bv[j], acc[i][j]);
    }
    __syncthreads();
  }
  float* pb = part + (size_t)kc * 2048 * 64;
#pragma unroll
  for (int i = 0; i < 4; ++i) {
    int m = m0 + tr + 16 * i;
    if (m >= M) continue;
#pragma unroll
    for (int j = 0; j < 4; ++j) {
      int n = tc + 16 * j;
      pb[(size_t)m * 64 + n] = acc[i][j];
    }
  }
}

// DBC[m][n] = sum_{kc<8} part[kc][m][n]
__global__ __launch_bounds__(256) void reduce_dbc(const float* __restrict__ part,
                                                  float* __restrict__ dbc, int M) {
  int idx = blockIdx.x * 256 + threadIdx.x;   // over M*64
  if (idx >= M * 64) return;
  float s = 0.f;
#pragma unroll
  for (int kc = 0; kc < 8; ++kc) s += part[(size_t)kc * 2048 * 64 + idx];
  dbc[idx] = s;
}

// -------- delta[m][d] = softplus( sum_{j<32} dBC[m][j]*W[d][j] + bias[d] ) ---
__global__ __launch_bounds__(256) void delta_kernel(const float* __restrict__ dBC,
                                                    const float* __restrict__ W,
                                                    const float* __restrict__ bias,
                                                    float* __restrict__ delta) {
  const int d = blockIdx.x * 256 + threadIdx.x;
  const int mBase = blockIdx.y * 16;
  __shared__ float rs[16][32];
  for (int idx = threadIdx.x; idx < 16 * 32; idx += 256) {
    int r = idx >> 5, c = idx & 31;
    rs[r][c] = dBC[(size_t)(mBase + r) * 64 + c];
  }
  __syncthreads();
  if (d >= D_) return;
  float w[32];
#pragma unroll
  for (int j = 0; j < 32; ++j) w[j] = W[d * 32 + j];
  const float bb = bias[d];
  for (int r = 0; r < 16; ++r) {
    float acc = bb;
#pragma unroll
    for (int j = 0; j < 32; ++j) acc = fmaf(rs[r][j], w[j], acc);
    float sp = (acc > 20.f) ? acc : log1pf(__expf(acc));
    delta[(size_t)(mBase + r) * D_ + d] = sp;
  }
}

// ------------------- selective scan, 3-pass chunked --------------------------
__global__ __launch_bounds__(256) void scan1(const float* __restrict__ delta,
                                             const float* __restrict__ x2,
                                             const float* __restrict__ dBC,
                                             const float* __restrict__ A_log,
                                             float* __restrict__ hfin,
                                             float* __restrict__ psum) {
  const int d = blockIdx.x * 256 + threadIdx.x;
  const int c = blockIdx.y, b = blockIdx.z;
  __shared__ float Bs[CH][16];
  for (int idx = threadIdx.x; idx < CH * 16; idx += 256) {
    int r = idx >> 4, n = idx & 15;
    Bs[r][n] = dBC[(size_t)(b * S_ + c * CH + r) * 64 + 32 + n];
  }
  __syncthreads();
  if (d >= D_) return;
  float a[16];
#pragma unroll
  for (int n = 0; n < 16; ++n) a[n] = -__expf(A_log[d * 16 + n]);
  float h[16] = {};
  float dsum = 0.f;
  const float* dp = delta + ((size_t)(b * S_ + c * CH)) * D_ + d;
  const float* xp = x2 + ((size_t)(b * S_ + c * CH)) * D_ + d;
  for (int l = 0; l < CH; ++l) {
    float dlt = dp[(size_t)l * D_];
    float xv = xp[(size_t)l * D_];
    dsum += dlt;
    float dx = dlt * xv;
#pragma unroll
    for (int n = 0; n < 16; ++n) {
      float da = __expf(dlt * a[n]);
      h[n] = fmaf(da, h[n], dx * Bs[l][n]);
    }
  }
  float* hb = hfin + (((size_t)b * NC + c) * D_ + d) * 16;
#pragma unroll
  for (int n = 0; n < 16; ++n) hb[n] = h[n];
  psum[((size_t)b * NC + c) * D_ + d] = dsum;
}

// one thread per (b,d,n): 32000 threads, serial over NC chunks
__global__ __launch_bounds__(256) void scan2(const float* __restrict__ hfin,
                                             const float* __restrict__ psum,
                                             const float* __restrict__ A_log,
                                             float* __restrict__ hin) {
  const int t = blockIdx.x * 256 + threadIdx.x;
  if (t >= B_ * D_ * 16) return;
  const int n = t & 15;
  const int bd = t >> 4;            // b*D_ + d
  const int b = bd / D_, d = bd - b * D_;
  const float a = -__expf(A_log[d * 16 + n]);
  float h = 0.f;
  for (int c = 0; c < NC; ++c) {
    const size_t base = ((size_t)b * NC + c) * D_ + d;
    hin[base * 16 + n] = h;
    float ps = psum[base];
    float hf = hfin[base * 16 + n];
    h = fmaf(__expf(a * ps), h, hf);
  }
}

__global__ __launch_bounds__(256) void scan3(const float* __restrict__ delta,
                                             const float* __restrict__ x2,
                                             const float* __restrict__ dBC,
                                             const float* __restrict__ A_log,
                                             const float* __restrict__ Dp,
                                             const float* __restrict__ hin,
                                             float* __restrict__ y) {
  const int d = blockIdx.x * 256 + threadIdx.x;
  const int c = blockIdx.y, b = blockIdx.z;
  __shared__ float Bs[CH][16];
  __shared__ float Cs[CH][16];
  for (int idx = threadIdx.x; idx < CH * 32; idx += 256) {
    int r = idx >> 5, col = idx & 31;
    float v = dBC[(size_t)(b * S_ + c * CH + r) * 64 + 32 + col];
    if (col < 16) Bs[r][col] = v;
    else Cs[r][col - 16] = v;
  }
  __syncthreads();
  if (d >= D_) return;
  float a[16];
#pragma unroll
  for (int n = 0; n < 16; ++n) a[n] = -__expf(A_log[d * 16 + n]);
  float h[16];
  const float* hp = hin + (((size_t)b * NC + c) * D_ + d) * 16;
#pragma unroll
  for (int n = 0; n < 16; ++n) h[n] = hp[n];
  const float dpv = Dp[d];
  const float* dp = delta + ((size_t)(b * S_ + c * CH)) * D_ + d;
  const float* xp = x2 + ((size_t)(b * S_ + c * CH)) * D_ + d;
  float* yp = y + ((size_t)(b * S_ + c * CH)) * D_ + d;
  for (int l = 0; l < CH; ++l) {
    float dlt = dp[(size_t)l * D_];
    float xv = xp[(size_t)l * D_];
    float dx = dlt * xv;
    float yv = 0.f;
#pragma unroll
    for (int n = 0; n < 16; ++n) {
      float da = __expf(dlt * a[n]);
      h[n] = fmaf(da, h[n], dx * Bs[l][n]);
      yv = fmaf(h[n], Cs[l][n], yv);
    }
    yp[(size_t)l * D_] = fmaf(dpv, xv, yv);
  }
}

// ---------- mult_bf: MBF[m][k] = bf16( silu(P1[m][k]) * Y[m][k] ), padded ----
__global__ __launch_bounds__(256) void mult_bf(const float* __restrict__ p1,
                                               const float* __restrict__ y,
                                               __hip_bfloat16* __restrict__ mbf) {
  int idx = blockIdx.x * 256 + threadIdx.x;  // over 2048*1024
  int m = idx >> 10, k = idx & 1023;
  float v = 0.f;
  if (m < B_ * S_ && k < D_) {
    float a = p1[(size_t)m * D_ + k];
    v = silu_f(a) * y[(size_t)m * D_ + k];
  }
  mbf[idx] = __float2bfloat16(v);
}

extern "C" void kernel_launch(void* const* d_in, const int* in_sizes, int n_in,
                              void* d_out, int out_size, void* d_ws, size_t ws_size,
                              hipStream_t stream) {
  const float* x        = (const float*)d_in[0];
  const float* proj_w   = (const float*)d_in[1];
  const float* proj_b   = (const float*)d_in[2];
  const float* conv_w   = (const float*)d_in[3];
  const float* deltaBC_w= (const float*)d_in[4];
  const float* dt_proj_w= (const float*)d_in[5];
  const float* dt_proj_b= (const float*)d_in[6];
  const float* A_log    = (const float*)d_in[7];
  const float* Dp       = (const float*)d_in[8];
  float* out = (float*)d_out;

  char* w8 = (char*)d_ws;
  float* P1    = (float*)(w8 + 0);          //  8,000,000 B
  float* X2    = (float*)(w8 + 8000000);    //  8,000,000
  float* DBC   = (float*)(w8 + 16000000);   //    512,000
  float* DELTA = (float*)(w8 + 16512000);   //  8,000,000
  float* Y     = (float*)(w8 + 24512000);   //  8,000,000
  __hip_bfloat16* XBF = (__hip_bfloat16*)(w8 + 32512000);  // [2048][1024]      4,194,304
  __hip_bfloat16* WBF = (__hip_bfloat16*)(w8 + 36706304);  // [1024][1024]      2,097,152
  __hip_bfloat16* CWB = (__hip_bfloat16*)(w8 + 38803456);  // [3][1024][1024]   6,291,456
  __hip_bfloat16* P1T = (__hip_bfloat16*)(w8 + 45094912);  // [2][1056][1024]   4,325,376
  __hip_bfloat16* MBF = (__hip_bfloat16*)(w8 + 49420288);  // [2048][1024]      4,194,304
  // scan scratch aliased over CWB+P1T (dead after conv_mfma):
  float* HFIN  = (float*)(w8 + 38803456);   // 5,120,000  (B*NC*D*16)
  float* PSUM  = (float*)(w8 + 43923456);   //   320,000
  float* HIN   = (float*)(w8 + 44243456);   // 5,120,000  -> ends 49,363,456
  // split-K partials aliased over MBF (dead until mult_bf):
  float* PART  = (float*)(w8 + 49420288);   // 4,194,304  [8][2048][64]
  // total ws use: 53,614,592 B

  dim3 blk(256);
  // bf16 conversions
  cvt_pad<<<dim3(8192), blk, 0, stream>>>(x, XBF, B_ * S_, D_);
  cvt_pad<<<dim3(4096), blk, 0, stream>>>(proj_w, WBF, D_, D_);
  cvt_conv<<<dim3(4096), blk, 0, stream>>>(conv_w, CWB);
  // 1. path1 = x @ proj_w.T + proj_b  (MFMA)
  gemm_mfma<<<dim3(32, 16), blk, 0, stream>>>(XBF, WBF, proj_b, P1, B_ * S_, D_, D_);
  // 1b. transpose path1 -> P1T (bf16, halo-padded)
  transpose_p1<<<dim3(32, 33, B_), blk, 0, stream>>>(P1, P1T);
  // 2. x2 = silu(conv(path1))  (implicit MFMA GEMM)
  conv_mfma<<<dim3(16, 16, B_), blk, 0, stream>>>(CWB, P1T, X2);
  // 3. dBC = x2 @ deltaBC_w.T  (f32 split-K + reduce)
  gemm_nt_splitk<<<dim3(32, 8), blk, 0, stream>>>(X2, deltaBC_w, PART, B_ * S_, 64, D_);
  reduce_dbc<<<dim3(500), blk, 0, stream>>>(PART, DBC, B_ * S_);
  // 4. delta = softplus(dBC[:, :32] @ dt_proj_w.T + dt_proj_b)
  delta_kernel<<<dim3(4, 125), blk, 0, stream>>>(DBC, dt_proj_w, dt_proj_b, DELTA);
  // 5-7. chunked selective scan -> Y
  scan1<<<dim3(4, NC, B_), blk, 0, stream>>>(DELTA, X2, DBC, A_log, HFIN, PSUM);
  scan2<<<dim3(125), blk, 0, stream>>>(HFIN, PSUM, A_log, HIN);
  scan3<<<dim3(4, NC, B_), blk, 0, stream>>>(DELTA, X2, DBC, A_log, Dp, HIN, Y);
  // 8. mult = silu(path1) * Y -> bf16 padded
  mult_bf<<<dim3(8192), blk, 0, stream>>>(P1, Y, MBF);
  // 9. out = mult @ proj_w.T + proj_b  (MFMA)
  gemm_mfma<<<dim3(32, 16), blk, 0, stream>>>(MBF, WBF, proj_b, out, B_ * S_, D_, D_);
}